// Round 2
// baseline (676.191 us; speedup 1.0000x reference)
//
#include <hip/hip_runtime.h>
#include <math.h>

// PhysioGAT pipeline on MI355X.
// Inputs (f32 unless noted): x[30000,3], edge_index[2,480000] (int32),
// batch[30000] (int32, sorted), W1[3,512], att_src1[8,64], att_dst1[8,64],
// b1[512], W2[512,128], att_src2[4,32], att_dst2[4,32], b2[128],
// Wfc[128,32], bfc[32], bn_gamma[32], bn_beta[32], Wheat[32,3], bheat[3],
// Wdehyd[32,2], bdehyd[2].
// Output: concat(heat[64,3], dehyd[64,2]) = 320 f32.

#define N_NODES 30000
#define N_GRAPHS 64

// ---------------- Layer-1 features: h1 = x @ W1, per-head attention dots ---
// grid = N, block = 512 (8 waves; wave w == head w, lane == channel)
__global__ __launch_bounds__(512) void k_feat1(
    const float* __restrict__ x, const float* __restrict__ W1,
    const float* __restrict__ asw, const float* __restrict__ adw,
    float* __restrict__ h1, float* __restrict__ a_s, float* __restrict__ a_d,
    int n)
{
    int node = blockIdx.x;
    int j = threadIdx.x;                      // 0..511 output feature
    float x0 = x[node * 3 + 0];
    float x1v = x[node * 3 + 1];
    float x2v = x[node * 3 + 2];
    float h = fmaf(x0, W1[j], fmaf(x1v, W1[512 + j], x2v * W1[1024 + j]));
    h1[(size_t)node * 512 + j] = h;
    float ps = h * asw[j];
    float pd = h * adw[j];
    #pragma unroll
    for (int off = 32; off; off >>= 1) {
        ps += __shfl_xor(ps, off);
        pd += __shfl_xor(pd, off);
    }
    if ((j & 63) == 0) {
        a_s[node * 8 + (j >> 6)] = ps;
        a_d[node * 8 + (j >> 6)] = pd;
    }
}

// ---------------- CSR build ------------------------------------------------
__global__ void k_deg(const int* __restrict__ ei, int* __restrict__ deg,
                      int E0, int n)
{
    int e = blockIdx.x * blockDim.x + threadIdx.x;
    int Et = E0 + n;
    if (e >= Et) return;
    int dst = (e < E0) ? ei[E0 + e] : (e - E0);
    atomicAdd(&deg[dst], 1);
}

// single block, 1024 threads: exclusive scan of deg -> rowstart + cursor.
// shuffle-based wave scans; only 3 barriers per 1024-chunk.
__global__ __launch_bounds__(1024) void k_scan(
    const int* __restrict__ deg, int* __restrict__ rowstart,
    int* __restrict__ cursor, int n)
{
    __shared__ int wsum[16];
    __shared__ int woff[17];
    __shared__ int carry_s;
    int tid = threadIdx.x, lane = tid & 63, wid = tid >> 6;
    if (tid == 0) carry_s = 0;
    __syncthreads();
    int nchunks = (n + 1023) >> 10;
    for (int c = 0; c < nchunks; ++c) {
        int i = (c << 10) + tid;
        int v = (i < n) ? deg[i] : 0;
        int s = v;                                   // wave inclusive scan
        #pragma unroll
        for (int off = 1; off < 64; off <<= 1) {
            int t = __shfl_up(s, off);
            if (lane >= off) s += t;
        }
        if (lane == 63) wsum[wid] = s;
        __syncthreads();
        if (wid == 0) {                              // scan the 16 wave sums
            int ws = (lane < 16) ? wsum[lane] : 0;
            #pragma unroll
            for (int off = 1; off < 16; off <<= 1) {
                int t = __shfl_up(ws, off);
                if (lane >= off) ws += t;
            }
            if (lane < 16) woff[lane + 1] = ws;
            if (lane == 0) woff[0] = 0;
        }
        __syncthreads();
        int excl = carry_s + woff[wid] + s - v;
        if (i < n) { rowstart[i] = excl; cursor[i] = excl; }
        __syncthreads();
        if (tid == 0) carry_s += woff[16];
        __syncthreads();
    }
    if (tid == 0) rowstart[n] = carry_s;
}

__global__ void k_fill(const int* __restrict__ ei, int* __restrict__ cursor,
                       int* __restrict__ csr, int E0, int n)
{
    int e = blockIdx.x * blockDim.x + threadIdx.x;
    int Et = E0 + n;
    if (e >= Et) return;
    int src, dst;
    if (e < E0) { src = ei[e]; dst = ei[E0 + e]; }
    else        { src = e - E0; dst = e - E0; }
    int pos = atomicAdd(&cursor[dst], 1);
    csr[pos] = src;
}

// ---------------- GAT layer 1 aggregation: wave per dst node ---------------
// Lane owns 8 CONTIGUOUS features lane*8..lane*8+7, all of head hd=lane>>3.
// Per edge: 1 exp + 2 coalesced dwordx4 loads per lane. No barriers.
__global__ __launch_bounds__(256) void k_gat1(
    const float* __restrict__ h1, const float* __restrict__ a_s,
    const float* __restrict__ a_d, const int* __restrict__ rowstart,
    const int* __restrict__ csr, const float* __restrict__ bias,
    float* __restrict__ x1, int n)
{
    int lane = threadIdx.x & 63;
    int node = blockIdx.x * 4 + (threadIdx.x >> 6);
    if (node >= n) return;
    int rs = rowstart[node], re = rowstart[node + 1];
    int hd = lane >> 3;                       // head this lane serves
    int slot = lane & 7;
    float adn = a_d[node * 8 + hd];

    // online softmax; 8 lanes (slots) share head hd
    float m = -1e30f, ssum = 0.f;
    for (int i = rs + slot; i < re; i += 8) {
        int src = csr[i];
        float e = a_s[src * 8 + hd] + adn;
        e = (e >= 0.f) ? e : 0.2f * e;
        if (e > m) { ssum = ssum * __expf(m - e) + 1.f; m = e; }
        else       { ssum += __expf(e - m); }
    }
    #pragma unroll
    for (int off = 1; off < 8; off <<= 1) {   // combine slots (bits 0..2)
        float mo = __shfl_xor(m, off);
        float so = __shfl_xor(ssum, off);
        float mn = fmaxf(m, mo);
        ssum = ssum * __expf(m - mn) + so * __expf(mo - mn);
        m = mn;
    }
    float inv = 1.f / ssum;

    float acc[8] = {0.f, 0.f, 0.f, 0.f, 0.f, 0.f, 0.f, 0.f};
    const float* hbase = h1 + (size_t)lane * 8;
    int src_next = (rs < re) ? csr[rs] : 0;
    for (int i = rs; i < re; ++i) {
        int src = src_next;
        if (i + 1 < re) src_next = csr[i + 1];      // prefetch index
        float e = a_s[src * 8 + hd] + adn;
        e = (e >= 0.f) ? e : 0.2f * e;
        float alpha = __expf(e - m) * inv;
        const float4* hp = (const float4*)(hbase + (size_t)src * 512);
        float4 hA = hp[0], hB = hp[1];
        acc[0] = fmaf(alpha, hA.x, acc[0]);
        acc[1] = fmaf(alpha, hA.y, acc[1]);
        acc[2] = fmaf(alpha, hA.z, acc[2]);
        acc[3] = fmaf(alpha, hA.w, acc[3]);
        acc[4] = fmaf(alpha, hB.x, acc[4]);
        acc[5] = fmaf(alpha, hB.y, acc[5]);
        acc[6] = fmaf(alpha, hB.z, acc[6]);
        acc[7] = fmaf(alpha, hB.w, acc[7]);
    }
    const float4* bp = (const float4*)(bias + lane * 8);
    float4 b0 = bp[0], b1v = bp[1];
    float4 o0, o1;
    o0.x = fmaxf(acc[0] + b0.x, 0.f);
    o0.y = fmaxf(acc[1] + b0.y, 0.f);
    o0.z = fmaxf(acc[2] + b0.z, 0.f);
    o0.w = fmaxf(acc[3] + b0.w, 0.f);
    o1.x = fmaxf(acc[4] + b1v.x, 0.f);
    o1.y = fmaxf(acc[5] + b1v.y, 0.f);
    o1.z = fmaxf(acc[6] + b1v.z, 0.f);
    o1.w = fmaxf(acc[7] + b1v.w, 0.f);
    float4* xp = (float4*)(x1 + (size_t)node * 512 + lane * 8);
    xp[0] = o0;
    xp[1] = o1;
}

// ---------------- Layer-2 features: h2 = x1 @ W2 (+ attention dots) --------
// block = 128 threads (j = output col), 16 nodes per block.
// x1 addresses are wave-uniform -> broadcast loads; W2 loads coalesced.
#define NT2 16
__global__ __launch_bounds__(128) void k_feat2(
    const float* __restrict__ x1, const float* __restrict__ W2,
    const float* __restrict__ asw, const float* __restrict__ adw,
    float* __restrict__ h2, float* __restrict__ a_s2, float* __restrict__ a_d2,
    int n)
{
    int j = threadIdx.x;                  // 0..127
    int n0 = blockIdx.x * NT2;
    float acc[NT2];
    #pragma unroll
    for (int t = 0; t < NT2; ++t) acc[t] = 0.f;

    for (int k = 0; k < 512; k += 4) {
        float w0 = W2[(k + 0) * 128 + j];
        float w1 = W2[(k + 1) * 128 + j];
        float w2 = W2[(k + 2) * 128 + j];
        float w3 = W2[(k + 3) * 128 + j];
        #pragma unroll
        for (int t = 0; t < NT2; ++t) {
            float4 xv = *(const float4*)(x1 + (size_t)(n0 + t) * 512 + k);
            acc[t] = fmaf(xv.x, w0,
                     fmaf(xv.y, w1,
                     fmaf(xv.z, w2,
                     fmaf(xv.w, w3, acc[t]))));
        }
    }

    int lane = threadIdx.x & 63;
    int hh = j >> 5;                      // head of this column (0..3)
    float wsj = asw[j], wdj = adw[j];
    #pragma unroll
    for (int t = 0; t < NT2; ++t) {
        h2[(size_t)(n0 + t) * 128 + j] = acc[t];
        float ps = acc[t] * wsj;
        float pd = acc[t] * wdj;
        #pragma unroll
        for (int off = 1; off < 32; off <<= 1) {
            ps += __shfl_xor(ps, off);
            pd += __shfl_xor(pd, off);
        }
        if ((lane & 31) == 0) {
            a_s2[(n0 + t) * 4 + hh] = ps;
            a_d2[(n0 + t) * 4 + hh] = pd;
        }
    }
}

// ---------------- GAT layer 2 aggregation + bias + relu + residual ---------
// Lane owns features 2*lane, 2*lane+1 (head hd=lane>>4). 1 exp/edge/lane.
__global__ __launch_bounds__(256) void k_gat2(
    const float* __restrict__ h2, const float* __restrict__ a_s,
    const float* __restrict__ a_d, const int* __restrict__ rowstart,
    const int* __restrict__ csr, const float* __restrict__ bias,
    const float* __restrict__ x1, float* __restrict__ hres, int n)
{
    int lane = threadIdx.x & 63;
    int node = blockIdx.x * 4 + (threadIdx.x >> 6);
    if (node >= n) return;
    int rs = rowstart[node], re = rowstart[node + 1];
    int hd = lane >> 4;                       // head (0..3)
    int slot = lane & 15;
    float adn = a_d[node * 4 + hd];

    float m = -1e30f, ssum = 0.f;
    for (int i = rs + slot; i < re; i += 16) {
        int src = csr[i];
        float e = a_s[src * 4 + hd] + adn;
        e = (e >= 0.f) ? e : 0.2f * e;
        if (e > m) { ssum = ssum * __expf(m - e) + 1.f; m = e; }
        else       { ssum += __expf(e - m); }
    }
    #pragma unroll
    for (int off = 1; off < 16; off <<= 1) {  // combine slots (bits 0..3)
        float mo = __shfl_xor(m, off);
        float so = __shfl_xor(ssum, off);
        float mn = fmaxf(m, mo);
        ssum = ssum * __expf(m - mn) + so * __expf(mo - mn);
        m = mn;
    }
    float inv = 1.f / ssum;

    float acc0 = 0.f, acc1 = 0.f;
    int src_next = (rs < re) ? csr[rs] : 0;
    for (int i = rs; i < re; ++i) {
        int src = src_next;
        if (i + 1 < re) src_next = csr[i + 1];
        float e = a_s[src * 4 + hd] + adn;
        e = (e >= 0.f) ? e : 0.2f * e;
        float alpha = __expf(e - m) * inv;
        float2 hv = *(const float2*)(h2 + (size_t)src * 128 + lane * 2);
        acc0 = fmaf(alpha, hv.x, acc0);
        acc1 = fmaf(alpha, hv.y, acc1);
    }
    float2 xv = *(const float2*)(x1 + (size_t)node * 512 + lane * 2);
    float2 o;
    o.x = xv.x + fmaxf(acc0 + bias[lane * 2 + 0], 0.f);
    o.y = xv.y + fmaxf(acc1 + bias[lane * 2 + 1], 0.f);
    *(float2*)(hres + (size_t)node * 128 + lane * 2) = o;
}

// ---------------- mean pool (batch is sorted) ------------------------------
__global__ __launch_bounds__(128) void k_pool(
    const float* __restrict__ hres, const int* __restrict__ batch,
    float* __restrict__ pooled, float* __restrict__ cnt, int n)
{
    int j = threadIdx.x;
    int n0 = blockIdx.x * 128;
    if (n0 >= n) return;
    int n1 = min(n0 + 128, n);
    int g = batch[n0];
    float acc = 0.f;
    int run = 0;
    for (int node = n0; node < n1; ++node) {
        int gb = batch[node];
        if (gb != g) {
            atomicAdd(&pooled[g * 128 + j], acc);
            if (j == 0) atomicAdd(&cnt[g], (float)run);
            acc = 0.f; run = 0; g = gb;
        }
        acc += hres[(size_t)node * 128 + j];
        run++;
    }
    atomicAdd(&pooled[g * 128 + j], acc);
    if (j == 0) atomicAdd(&cnt[g], (float)run);
}

// ---------------- FC + BN + ReLU + two heads (tiny, one block) -------------
__global__ __launch_bounds__(1024) void k_head(
    const float* __restrict__ pooled, const float* __restrict__ cnt,
    const float* __restrict__ Wfc, const float* __restrict__ bfc,
    const float* __restrict__ gamma, const float* __restrict__ beta,
    const float* __restrict__ Wheat, const float* __restrict__ bheat,
    const float* __restrict__ Wdehyd, const float* __restrict__ bdehyd,
    float* __restrict__ out)
{
    __shared__ float z[N_GRAPHS * 32];
    __shared__ float mu_s[32], rstd_s[32];
    int t = threadIdx.x;
    for (int idx = t; idx < N_GRAPHS * 32; idx += 1024) {
        int g = idx >> 5, j = idx & 31;
        float c = cnt[g];
        c = c < 1.f ? 1.f : c;
        float s = 0.f;
        for (int k = 0; k < 128; ++k)
            s = fmaf(pooled[g * 128 + k], Wfc[k * 32 + j], s);
        z[idx] = s / c + bfc[j];
    }
    __syncthreads();
    if (t < 32) {
        float mu = 0.f;
        for (int g = 0; g < N_GRAPHS; ++g) mu += z[g * 32 + t];
        mu *= (1.f / N_GRAPHS);
        float var = 0.f;
        for (int g = 0; g < N_GRAPHS; ++g) {
            float d = z[g * 32 + t] - mu;
            var = fmaf(d, d, var);
        }
        var *= (1.f / N_GRAPHS);
        mu_s[t] = mu;
        rstd_s[t] = 1.f / sqrtf(var + 1e-5f);
    }
    __syncthreads();
    for (int idx = t; idx < N_GRAPHS * 32; idx += 1024) {
        int j = idx & 31;
        float v = gamma[j] * (z[idx] - mu_s[j]) * rstd_s[j] + beta[j];
        z[idx] = v > 0.f ? v : 0.f;
    }
    __syncthreads();
    if (t < N_GRAPHS * 3) {
        int g = t / 3, r = t - g * 3;
        float s = 0.f;
        for (int j2 = 0; j2 < 32; ++j2)
            s = fmaf(z[g * 32 + j2], Wheat[j2 * 3 + r], s);
        out[t] = s + bheat[r];
    } else if (t < N_GRAPHS * 3 + N_GRAPHS * 2) {
        int idx = t - N_GRAPHS * 3;
        int g = idx >> 1, r = idx & 1;
        float s = 0.f;
        for (int j2 = 0; j2 < 32; ++j2)
            s = fmaf(z[g * 32 + j2], Wdehyd[j2 * 2 + r], s);
        out[N_GRAPHS * 3 + idx] = s + bdehyd[r];
    }
}

// ---------------- launch ---------------------------------------------------
extern "C" void kernel_launch(void* const* d_in, const int* in_sizes, int n_in,
                              void* d_out, int out_size, void* d_ws, size_t ws_size,
                              hipStream_t stream)
{
    const float* x      = (const float*)d_in[0];
    const int*   ei     = (const int*)d_in[1];
    const int*   batch  = (const int*)d_in[2];
    const float* W1     = (const float*)d_in[3];
    const float* as1w   = (const float*)d_in[4];
    const float* ad1w   = (const float*)d_in[5];
    const float* b1     = (const float*)d_in[6];
    const float* W2     = (const float*)d_in[7];
    const float* as2w   = (const float*)d_in[8];
    const float* ad2w   = (const float*)d_in[9];
    const float* b2     = (const float*)d_in[10];
    const float* Wfc    = (const float*)d_in[11];
    const float* bfc    = (const float*)d_in[12];
    const float* gamma  = (const float*)d_in[13];
    const float* beta   = (const float*)d_in[14];
    const float* Wheat  = (const float*)d_in[15];
    const float* bheat  = (const float*)d_in[16];
    const float* Wdehyd = (const float*)d_in[17];
    const float* bdehyd = (const float*)d_in[18];
    float* out = (float*)d_out;

    const int N = N_NODES;
    const int E0 = in_sizes[1] / 2;
    const int Et = E0 + N;
    const int G = N_GRAPHS;

    char* w = (char*)d_ws;
    auto alloc = [&](size_t bytes) -> char* {
        char* p = w;
        w += (bytes + 255) & ~(size_t)255;
        return p;
    };
    float* h1    = (float*)alloc((size_t)N * 512 * 4);  // reused: h2, hres
    float* x1    = (float*)alloc((size_t)N * 512 * 4);
    float* a_s1  = (float*)alloc((size_t)N * 8 * 4);
    float* a_d1  = (float*)alloc((size_t)N * 8 * 4);
    float* a_s2  = (float*)alloc((size_t)N * 4 * 4);
    float* a_d2  = (float*)alloc((size_t)N * 4 * 4);
    int* deg     = (int*)alloc((size_t)(N + 1) * 4);
    int* rowstart= (int*)alloc((size_t)(N + 1) * 4);
    int* cursor  = (int*)alloc((size_t)N * 4);
    int* csr     = (int*)alloc((size_t)Et * 4);
    float* pooled= (float*)alloc((size_t)G * 128 * 4);
    float* cntf  = (float*)alloc((size_t)G * 4);
    // h1 buffer recycling (layer-1 h1 dead after k_gat1):
    float* h2   = h1;                       // [N,128]
    float* hres = h1 + (size_t)N * 128;     // [N,128]

    hipMemsetAsync(deg, 0, (size_t)(N + 1) * 4, stream);
    hipMemsetAsync(pooled, 0, (size_t)G * 128 * 4, stream);
    hipMemsetAsync(cntf, 0, (size_t)G * 4, stream);

    k_feat1<<<N, 512, 0, stream>>>(x, W1, as1w, ad1w, h1, a_s1, a_d1, N);
    k_deg<<<(Et + 255) / 256, 256, 0, stream>>>(ei, deg, E0, N);
    k_scan<<<1, 1024, 0, stream>>>(deg, rowstart, cursor, N);
    k_fill<<<(Et + 255) / 256, 256, 0, stream>>>(ei, cursor, csr, E0, N);
    k_gat1<<<(N + 3) / 4, 256, 0, stream>>>(h1, a_s1, a_d1, rowstart, csr, b1, x1, N);
    k_feat2<<<N / NT2, 128, 0, stream>>>(x1, W2, as2w, ad2w, h2, a_s2, a_d2, N);
    k_gat2<<<(N + 3) / 4, 256, 0, stream>>>(h2, a_s2, a_d2, rowstart, csr, b2, x1, hres, N);
    k_pool<<<(N + 127) / 128, 128, 0, stream>>>(hres, batch, pooled, cntf, N);
    k_head<<<1, 1024, 0, stream>>>(pooled, cntf, Wfc, bfc, gamma, beta,
                                   Wheat, bheat, Wdehyd, bdehyd, out);
}

// Round 5
// 417.834 us; speedup vs baseline: 1.6183x; 1.6183x over previous
//
#include <hip/hip_runtime.h>
#include <math.h>

// PhysioGAT pipeline on MI355X.
// Layer-1 trick: h1 = x@W1 is linear in 3-dim x, so the alpha-weighted
// neighbor sum is (sum alpha*x[src]) @ W1 — h1 is never materialized.
// Output: concat(heat[64,3], dehyd[64,2]) = 320 f32.

#define N_NODES 30000
#define N_GRAPHS 64

// ---------------- Layer-1 attention logits: a_s1/a_d1[n,8] -----------------
// a_s[n,h] = x[n,:] . P_s[:,h],  P_s[d,h] = sum_c W1[d,h*64+c]*att_src[h,c]
__global__ __launch_bounds__(256) void k_att1(
    const float* __restrict__ x, const float* __restrict__ W1,
    const float* __restrict__ asw, const float* __restrict__ adw,
    float* __restrict__ a_s, float* __restrict__ a_d, int n)
{
    __shared__ float Ps[24], Pd[24];          // idx = d*8 + h
    int t = threadIdx.x;
    if (t < 48) {
        int which = t / 24;                   // 0 -> Ps, 1 -> Pd
        int idx = t - which * 24;
        int d = idx >> 3, h = idx & 7;
        const float* av = (which ? adw : asw) + h * 64;
        const float* wr = W1 + d * 512 + h * 64;
        float s = 0.f;
        #pragma unroll 8
        for (int c = 0; c < 64; ++c) s = fmaf(wr[c], av[c], s);
        (which ? Pd : Ps)[idx] = s;
    }
    __syncthreads();
    int node = blockIdx.x * 256 + t;
    if (node >= n) return;
    float x0 = x[node * 3 + 0];
    float x1v = x[node * 3 + 1];
    float x2v = x[node * 3 + 2];
    #pragma unroll
    for (int h = 0; h < 8; ++h) {
        a_s[node * 8 + h] = fmaf(x0, Ps[h], fmaf(x1v, Ps[8 + h], x2v * Ps[16 + h]));
        a_d[node * 8 + h] = fmaf(x0, Pd[h], fmaf(x1v, Pd[8 + h], x2v * Pd[16 + h]));
    }
}

// ---------------- CSR build ------------------------------------------------
__global__ void k_deg(const int* __restrict__ ei, int* __restrict__ deg,
                      int E0, int n)
{
    int e = blockIdx.x * blockDim.x + threadIdx.x;
    int Et = E0 + n;
    if (e >= Et) return;
    int dst = (e < E0) ? ei[E0 + e] : (e - E0);
    atomicAdd(&deg[dst], 1);
}

__global__ __launch_bounds__(1024) void k_scan(
    const int* __restrict__ deg, int* __restrict__ rowstart,
    int* __restrict__ cursor, int n)
{
    __shared__ int wsum[16];
    __shared__ int woff[17];
    __shared__ int carry_s;
    int tid = threadIdx.x, lane = tid & 63, wid = tid >> 6;
    if (tid == 0) carry_s = 0;
    __syncthreads();
    int nchunks = (n + 1023) >> 10;
    for (int c = 0; c < nchunks; ++c) {
        int i = (c << 10) + tid;
        int v = (i < n) ? deg[i] : 0;
        int s = v;                                   // wave inclusive scan
        #pragma unroll
        for (int off = 1; off < 64; off <<= 1) {
            int t = __shfl_up(s, off);
            if (lane >= off) s += t;
        }
        if (lane == 63) wsum[wid] = s;
        __syncthreads();
        if (wid == 0) {                              // scan the 16 wave sums
            int ws = (lane < 16) ? wsum[lane] : 0;
            #pragma unroll
            for (int off = 1; off < 16; off <<= 1) {
                int t = __shfl_up(ws, off);
                if (lane >= off) ws += t;
            }
            if (lane < 16) woff[lane + 1] = ws;
            if (lane == 0) woff[0] = 0;
        }
        __syncthreads();
        int excl = carry_s + woff[wid] + s - v;
        if (i < n) { rowstart[i] = excl; cursor[i] = excl; }
        __syncthreads();
        if (tid == 0) carry_s += woff[16];
        __syncthreads();
    }
    if (tid == 0) rowstart[n] = carry_s;
}

__global__ void k_fill(const int* __restrict__ ei, int* __restrict__ cursor,
                       int* __restrict__ csr, int E0, int n)
{
    int e = blockIdx.x * blockDim.x + threadIdx.x;
    int Et = E0 + n;
    if (e >= Et) return;
    int src, dst;
    if (e < E0) { src = ei[e]; dst = ei[E0 + e]; }
    else        { src = e - E0; dst = e - E0; }
    int pos = atomicAdd(&cursor[dst], 1);
    csr[pos] = src;
}

// ---------------- GAT layer 1: online softmax over S = sum alpha*x[src] ----
// wave per node; hd = lane>>3 (8 heads), slot = lane&7 strides edges.
// Epilogue: x1[node, hd*64 + c] = relu(S . W1[:, col] / ssum + bias).
__global__ __launch_bounds__(256) void k_gat1(
    const float* __restrict__ x, const float* __restrict__ W1,
    const float* __restrict__ a_s, const float* __restrict__ a_d,
    const int* __restrict__ rowstart, const int* __restrict__ csr,
    const float* __restrict__ bias, float* __restrict__ x1, int n)
{
    int lane = threadIdx.x & 63;
    int node = blockIdx.x * 4 + (threadIdx.x >> 6);
    if (node >= n) return;
    int rs = rowstart[node], re = rowstart[node + 1];
    int hd = lane >> 3;
    int slot = lane & 7;
    float adn = a_d[node * 8 + hd];

    float m = -1e30f, ssum = 0.f, S0 = 0.f, S1 = 0.f, S2 = 0.f;
    for (int i = rs + slot; i < re; i += 8) {
        int src = csr[i];
        float e = a_s[src * 8 + hd] + adn;
        e = (e >= 0.f) ? e : 0.2f * e;
        float x0 = x[src * 3 + 0];
        float x1v = x[src * 3 + 1];
        float x2v = x[src * 3 + 2];
        float mn = fmaxf(m, e);
        float sc = __expf(m - mn);
        float wgt = __expf(e - mn);
        ssum = fmaf(ssum, sc, wgt);
        S0 = fmaf(S0, sc, wgt * x0);
        S1 = fmaf(S1, sc, wgt * x1v);
        S2 = fmaf(S2, sc, wgt * x2v);
        m = mn;
    }
    #pragma unroll
    for (int off = 1; off < 8; off <<= 1) {   // merge 8 slots of this head
        float mo = __shfl_xor(m, off);
        float so = __shfl_xor(ssum, off);
        float t0 = __shfl_xor(S0, off);
        float t1 = __shfl_xor(S1, off);
        float t2 = __shfl_xor(S2, off);
        float mn = fmaxf(m, mo);
        float scA = __expf(m - mn);
        float scB = __expf(mo - mn);
        ssum = ssum * scA + so * scB;
        S0 = S0 * scA + t0 * scB;
        S1 = S1 * scA + t1 * scB;
        S2 = S2 * scA + t2 * scB;
        m = mn;
    }
    float inv = 1.f / ssum;
    S0 *= inv; S1 *= inv; S2 *= inv;

    // epilogue: features j = lane*8 .. lane*8+7 (all in head hd)
    const float4* w0p = (const float4*)(W1 + lane * 8);
    const float4* w1p = (const float4*)(W1 + 512 + lane * 8);
    const float4* w2p = (const float4*)(W1 + 1024 + lane * 8);
    const float4* bp  = (const float4*)(bias + lane * 8);
    float4* xp = (float4*)(x1 + (size_t)node * 512 + lane * 8);
    #pragma unroll
    for (int q = 0; q < 2; ++q) {
        float4 w0 = w0p[q], w1 = w1p[q], w2 = w2p[q], b = bp[q];
        float4 o;
        o.x = fmaxf(fmaf(S0, w0.x, fmaf(S1, w1.x, fmaf(S2, w2.x, b.x))), 0.f);
        o.y = fmaxf(fmaf(S0, w0.y, fmaf(S1, w1.y, fmaf(S2, w2.y, b.y))), 0.f);
        o.z = fmaxf(fmaf(S0, w0.z, fmaf(S1, w1.z, fmaf(S2, w2.z, b.z))), 0.f);
        o.w = fmaxf(fmaf(S0, w0.w, fmaf(S1, w1.w, fmaf(S2, w2.w, b.w))), 0.f);
        xp[q] = o;
    }
}

// ---------------- Layer-2 GEMM: h2[30000,128] = x1[30000,512] @ W2[512,128]
// 256 threads, 128x128 block tile, 8x8 register tile per thread. No LDS.
#define BM2 128
__global__ __launch_bounds__(256) void k_gemm2(
    const float* __restrict__ x1, const float* __restrict__ W2,
    float* __restrict__ h2, int n)
{
    int tid = threadIdx.x;
    int tr = tid >> 4;                 // 0..15 row group
    int tc = tid & 15;                 // 0..15 col group
    int bm = blockIdx.x * BM2;

    float acc[8][8];
    #pragma unroll
    for (int r = 0; r < 8; ++r)
        #pragma unroll
        for (int c = 0; c < 8; ++c) acc[r][c] = 0.f;

    const float* arow[8];
    #pragma unroll
    for (int r = 0; r < 8; ++r) {
        int row = bm + tr * 8 + r;
        row = row < n ? row : (n - 1);           // clamp (writes guarded)
        arow[r] = x1 + (size_t)row * 512;
    }
    const float* bcol = W2 + tc * 8;

    for (int k = 0; k < 512; k += 4) {
        float a_[8][4];
        #pragma unroll
        for (int r = 0; r < 8; ++r) {
            float4 av = *(const float4*)(arow[r] + k);
            a_[r][0] = av.x; a_[r][1] = av.y; a_[r][2] = av.z; a_[r][3] = av.w;
        }
        float b_[4][8];
        #pragma unroll
        for (int kk = 0; kk < 4; ++kk) {
            float4 b0 = *(const float4*)(bcol + (size_t)(k + kk) * 128);
            float4 b1 = *(const float4*)(bcol + (size_t)(k + kk) * 128 + 4);
            b_[kk][0] = b0.x; b_[kk][1] = b0.y; b_[kk][2] = b0.z; b_[kk][3] = b0.w;
            b_[kk][4] = b1.x; b_[kk][5] = b1.y; b_[kk][6] = b1.z; b_[kk][7] = b1.w;
        }
        #pragma unroll
        for (int kk = 0; kk < 4; ++kk)
            #pragma unroll
            for (int r = 0; r < 8; ++r)
                #pragma unroll
                for (int c = 0; c < 8; ++c)
                    acc[r][c] = fmaf(a_[r][kk], b_[kk][c], acc[r][c]);
    }

    #pragma unroll
    for (int r = 0; r < 8; ++r) {
        int row = bm + tr * 8 + r;
        if (row < n) {
            float4 o0, o1;
            o0.x = acc[r][0]; o0.y = acc[r][1]; o0.z = acc[r][2]; o0.w = acc[r][3];
            o1.x = acc[r][4]; o1.y = acc[r][5]; o1.z = acc[r][6]; o1.w = acc[r][7];
            float4* hp = (float4*)(h2 + (size_t)row * 128 + tc * 8);
            hp[0] = o0;
            hp[1] = o1;
        }
    }
}

// ---------------- Layer-2 attention dots: a_s2/a_d2[n,4] -------------------
__global__ __launch_bounds__(256) void k_att2(
    const float* __restrict__ h2, const float* __restrict__ asw,
    const float* __restrict__ adw, float* __restrict__ a_s2,
    float* __restrict__ a_d2, int n)
{
    int lane = threadIdx.x & 63;
    int node = blockIdx.x * 4 + (threadIdx.x >> 6);
    if (node >= n) return;
    float2 hv = *(const float2*)(h2 + (size_t)node * 128 + lane * 2);
    float2 ws = *(const float2*)(asw + lane * 2);
    float2 wd = *(const float2*)(adw + lane * 2);
    float ps = hv.x * ws.x + hv.y * ws.y;
    float pd = hv.x * wd.x + hv.y * wd.y;
    #pragma unroll
    for (int off = 1; off < 16; off <<= 1) {   // reduce within 16-lane head
        ps += __shfl_xor(ps, off);
        pd += __shfl_xor(pd, off);
    }
    if ((lane & 15) == 0) {
        int hd = lane >> 4;
        a_s2[node * 4 + hd] = ps;
        a_d2[node * 4 + hd] = pd;
    }
}

// ---------------- GAT layer 2: single-pass online softmax + residual -------
// Lane owns features 2*lane, 2*lane+1 (head hd=lane>>4). All lanes iterate
// all edges; (m,ssum) duplicated within a head group -> no cross-lane reduce.
__global__ __launch_bounds__(256) void k_gat2(
    const float* __restrict__ h2, const float* __restrict__ a_s,
    const float* __restrict__ a_d, const int* __restrict__ rowstart,
    const int* __restrict__ csr, const float* __restrict__ bias,
    const float* __restrict__ x1, float* __restrict__ hres, int n)
{
    int lane = threadIdx.x & 63;
    int node = blockIdx.x * 4 + (threadIdx.x >> 6);
    if (node >= n) return;
    int rs = rowstart[node], re = rowstart[node + 1];
    int hd = lane >> 4;                       // head (0..3)
    float adn = a_d[node * 4 + hd];

    float m = -1e30f, ssum = 0.f, acc0 = 0.f, acc1 = 0.f;
    int src_next = (rs < re) ? csr[rs] : 0;
    for (int i = rs; i < re; ++i) {
        int src = src_next;
        if (i + 1 < re) src_next = csr[i + 1];
        float e = a_s[src * 4 + hd] + adn;
        e = (e >= 0.f) ? e : 0.2f * e;
        float2 hv = *(const float2*)(h2 + (size_t)src * 128 + lane * 2);
        float mn = fmaxf(m, e);
        float sc = __expf(m - mn);
        float wgt = __expf(e - mn);
        ssum = fmaf(ssum, sc, wgt);
        acc0 = fmaf(acc0, sc, wgt * hv.x);
        acc1 = fmaf(acc1, sc, wgt * hv.y);
        m = mn;
    }
    float inv = 1.f / ssum;
    float2 xv = *(const float2*)(x1 + (size_t)node * 512 + lane * 2);
    float2 o;
    o.x = xv.x + fmaxf(fmaf(acc0, inv, bias[lane * 2 + 0]), 0.f);
    o.y = xv.y + fmaxf(fmaf(acc1, inv, bias[lane * 2 + 1]), 0.f);
    *(float2*)(hres + (size_t)node * 128 + lane * 2) = o;
}

// ---------------- mean pool (batch is sorted) ------------------------------
__global__ __launch_bounds__(128) void k_pool(
    const float* __restrict__ hres, const int* __restrict__ batch,
    float* __restrict__ pooled, float* __restrict__ cnt, int n)
{
    int j = threadIdx.x;
    int n0 = blockIdx.x * 128;
    if (n0 >= n) return;
    int n1 = min(n0 + 128, n);
    int g = batch[n0];
    float acc = 0.f;
    int run = 0;
    for (int node = n0; node < n1; ++node) {
        int gb = batch[node];
        if (gb != g) {
            atomicAdd(&pooled[g * 128 + j], acc);
            if (j == 0) atomicAdd(&cnt[g], (float)run);
            acc = 0.f; run = 0; g = gb;
        }
        acc += hres[(size_t)node * 128 + j];
        run++;
    }
    atomicAdd(&pooled[g * 128 + j], acc);
    if (j == 0) atomicAdd(&cnt[g], (float)run);
}

// ---------------- FC + BN + ReLU + two heads (tiny, one block) -------------
__global__ __launch_bounds__(1024) void k_head(
    const float* __restrict__ pooled, const float* __restrict__ cnt,
    const float* __restrict__ Wfc, const float* __restrict__ bfc,
    const float* __restrict__ gamma, const float* __restrict__ beta,
    const float* __restrict__ Wheat, const float* __restrict__ bheat,
    const float* __restrict__ Wdehyd, const float* __restrict__ bdehyd,
    float* __restrict__ out)
{
    __shared__ float z[N_GRAPHS * 32];
    __shared__ float mu_s[32], rstd_s[32];
    int t = threadIdx.x;
    for (int idx = t; idx < N_GRAPHS * 32; idx += 1024) {
        int g = idx >> 5, j = idx & 31;
        float c = cnt[g];
        c = c < 1.f ? 1.f : c;
        float s = 0.f;
        for (int k = 0; k < 128; ++k)
            s = fmaf(pooled[g * 128 + k], Wfc[k * 32 + j], s);
        z[idx] = s / c + bfc[j];
    }
    __syncthreads();
    if (t < 32) {
        float mu = 0.f;
        for (int g = 0; g < N_GRAPHS; ++g) mu += z[g * 32 + t];
        mu *= (1.f / N_GRAPHS);
        float var = 0.f;
        for (int g = 0; g < N_GRAPHS; ++g) {
            float d = z[g * 32 + t] - mu;
            var = fmaf(d, d, var);
        }
        var *= (1.f / N_GRAPHS);
        mu_s[t] = mu;
        rstd_s[t] = 1.f / sqrtf(var + 1e-5f);
    }
    __syncthreads();
    for (int idx = t; idx < N_GRAPHS * 32; idx += 1024) {
        int j = idx & 31;
        float v = gamma[j] * (z[idx] - mu_s[j]) * rstd_s[j] + beta[j];
        z[idx] = v > 0.f ? v : 0.f;
    }
    __syncthreads();
    if (t < N_GRAPHS * 3) {
        int g = t / 3, r = t - g * 3;
        float s = 0.f;
        for (int j2 = 0; j2 < 32; ++j2)
            s = fmaf(z[g * 32 + j2], Wheat[j2 * 3 + r], s);
        out[t] = s + bheat[r];
    } else if (t < N_GRAPHS * 3 + N_GRAPHS * 2) {
        int idx = t - N_GRAPHS * 3;
        int g = idx >> 1, r = idx & 1;
        float s = 0.f;
        for (int j2 = 0; j2 < 32; ++j2)
            s = fmaf(z[g * 32 + j2], Wdehyd[j2 * 2 + r], s);
        out[N_GRAPHS * 3 + idx] = s + bdehyd[r];
    }
}

// ---------------- launch ---------------------------------------------------
extern "C" void kernel_launch(void* const* d_in, const int* in_sizes, int n_in,
                              void* d_out, int out_size, void* d_ws, size_t ws_size,
                              hipStream_t stream)
{
    const float* x      = (const float*)d_in[0];
    const int*   ei     = (const int*)d_in[1];
    const int*   batch  = (const int*)d_in[2];
    const float* W1     = (const float*)d_in[3];
    const float* as1w   = (const float*)d_in[4];
    const float* ad1w   = (const float*)d_in[5];
    const float* b1     = (const float*)d_in[6];
    const float* W2     = (const float*)d_in[7];
    const float* as2w   = (const float*)d_in[8];
    const float* ad2w   = (const float*)d_in[9];
    const float* b2     = (const float*)d_in[10];
    const float* Wfc    = (const float*)d_in[11];
    const float* bfc    = (const float*)d_in[12];
    const float* gamma  = (const float*)d_in[13];
    const float* beta   = (const float*)d_in[14];
    const float* Wheat  = (const float*)d_in[15];
    const float* bheat  = (const float*)d_in[16];
    const float* Wdehyd = (const float*)d_in[17];
    const float* bdehyd = (const float*)d_in[18];
    float* out = (float*)d_out;

    const int N = N_NODES;
    const int E0 = in_sizes[1] / 2;
    const int Et = E0 + N;
    const int G = N_GRAPHS;

    char* w = (char*)d_ws;
    auto alloc = [&](size_t bytes) -> char* {
        char* p = w;
        w += (bytes + 255) & ~(size_t)255;
        return p;
    };
    float* x1    = (float*)alloc((size_t)N * 512 * 4);
    float* h2    = (float*)alloc((size_t)N * 128 * 4);
    float* hres  = (float*)alloc((size_t)N * 128 * 4);
    float* a_s1  = (float*)alloc((size_t)N * 8 * 4);
    float* a_d1  = (float*)alloc((size_t)N * 8 * 4);
    float* a_s2  = (float*)alloc((size_t)N * 4 * 4);
    float* a_d2  = (float*)alloc((size_t)N * 4 * 4);
    int* deg     = (int*)alloc((size_t)(N + 1) * 4);
    int* rowstart= (int*)alloc((size_t)(N + 1) * 4);
    int* cursor  = (int*)alloc((size_t)N * 4);
    int* csr     = (int*)alloc((size_t)Et * 4);
    float* pooled= (float*)alloc((size_t)G * 128 * 4);
    float* cntf  = (float*)alloc((size_t)G * 4);

    hipMemsetAsync(deg, 0, (size_t)(N + 1) * 4, stream);
    hipMemsetAsync(pooled, 0, (size_t)G * 128 * 4, stream);
    hipMemsetAsync(cntf, 0, (size_t)G * 4, stream);

    k_att1<<<(N + 255) / 256, 256, 0, stream>>>(x, W1, as1w, ad1w, a_s1, a_d1, N);
    k_deg<<<(Et + 255) / 256, 256, 0, stream>>>(ei, deg, E0, N);
    k_scan<<<1, 1024, 0, stream>>>(deg, rowstart, cursor, N);
    k_fill<<<(Et + 255) / 256, 256, 0, stream>>>(ei, cursor, csr, E0, N);
    k_gat1<<<(N + 3) / 4, 256, 0, stream>>>(x, W1, a_s1, a_d1, rowstart, csr, b1, x1, N);
    k_gemm2<<<(N + BM2 - 1) / BM2, 256, 0, stream>>>(x1, W2, h2, N);
    k_att2<<<(N + 3) / 4, 256, 0, stream>>>(h2, as2w, ad2w, a_s2, a_d2, N);
    k_gat2<<<(N + 3) / 4, 256, 0, stream>>>(h2, a_s2, a_d2, rowstart, csr, b2, x1, hres, N);
    k_pool<<<(N + 127) / 128, 128, 0, stream>>>(hres, batch, pooled, cntf, N);
    k_head<<<1, 1024, 0, stream>>>(pooled, cntf, Wfc, bfc, gamma, beta,
                                   Wheat, bheat, Wdehyd, bdehyd, out);
}